// Round 10
// baseline (3328.801 us; speedup 1.0000x reference)
//
#include <hip/hip_runtime.h>
#include <hip/hip_bf16.h>
#include <stdint.h>

#define B_  256
#define DIN 128
#define H_  256
#define T_  512
#define F_  64
#define ZW  1024   // 4*H

#define WGPC 8     // workgroups per cluster (32 h-cols each)
#define NWG  128   // 16 clusters x 8 wgs
#define NTHR 512   // 8 waves

typedef __attribute__((ext_vector_type(8))) short bf16x8;
typedef __attribute__((ext_vector_type(4))) float f32x4;

#define SWZ(x,imm) __int_as_float(__builtin_amdgcn_ds_swizzle(__float_as_int(x),(imm)))

__device__ __forceinline__ unsigned short f2bf(float f){
  uint32_t u = __float_as_uint(f);
  uint32_t r = (u + 0x7fffu + ((u >> 16) & 1u)) >> 16;   // RNE
  return (unsigned short)r;
}
// single-expf activation: g2 ? tanh(z) : sigmoid(z); overflow-safe
__device__ __forceinline__ float gate_act(float z, bool g2){
  float a = g2 ? (-2.f * fabsf(z)) : (-z);
  float t = __expf(a);
  float r = (g2 ? (1.f - t) : 1.f) / (1.f + t);
  return g2 ? copysignf(r, z) : r;
}
__device__ __forceinline__ float tanh_fast(float x){
  float t = __expf(-2.0f * fabsf(x));
  return copysignf((1.0f - t) / (1.0f + t), x);
}

// plain B-fragment gather (head): col = lane&15, k = kbase + (lane>>4)*8 + j
__device__ __forceinline__ bf16x8 load_wfrag(const float* W, int ld, int col, int kbase, int lane){
  int k0 = kbase + ((lane >> 4) << 3);
  int n  = col + (lane & 15);
  bf16x8 r;
#pragma unroll
  for(int j = 0; j < 8; ++j)
    r[j] = (short)f2bf(W[(size_t)(k0 + j) * ld + n]);
  return r;
}
// gate-interleaved B-fragment: tile col c -> weight col (c&3)*H + jbase + (c>>2)
__device__ __forceinline__ bf16x8 load_gfrag(const float* W, int jbase, int kbase, int lane){
  int k0 = kbase + ((lane >> 4) << 3);
  int c  = lane & 15;
  int n  = (c & 3) * H_ + jbase + (c >> 2);
  bf16x8 r;
#pragma unroll
  for(int j = 0; j < 8; ++j)
    r[j] = (short)f2bf(W[(size_t)(k0 + j) * ZW + n]);
  return r;
}

__global__ __launch_bounds__(NTHR, 1)
void lstm_fused(const float* __restrict__ in,  const float* __restrict__ W_in, const float* __restrict__ b_in,
                const float* __restrict__ Wx1, const float* __restrict__ Wh1,  const float* __restrict__ b1,
                const float* __restrict__ Wx2, const float* __restrict__ Wh2,  const float* __restrict__ b2,
                const float* __restrict__ W_out, const float* __restrict__ b_out,
                float* __restrict__ out,
                uint32_t* __restrict__ flags, uint64_t* __restrict__ h1buf, uint64_t* __restrict__ h2buf)
{
  const int tid  = threadIdx.x;
  const int lane = tid & 63;
  const int wv   = tid >> 6;          // wave 0..7
  const int wg   = blockIdx.x;
  const int cid  = wg >> 3;           // cluster = batch tile of 16 rows
  const int w16  = wg & 7;            // h-col slice (32 cols) within cluster
  const int rb   = cid * 16;
  const int jc   = w16 * 32;

  __shared__ float ins[16][DIN];      // prologue only
  __shared__ float xs[16][H_];        // prologue only
  __shared__ float zx1s[4][16][32];   // prologue only (this wg's 32 cols)
  __shared__ unsigned short h1s[16][264];  // staged h1 tile (+8 pad)
  __shared__ unsigned short h2s[16][264];  // staged h2 tile

  // ---------------- prologue ----------------
  for(int idx = tid; idx < 16 * DIN; idx += NTHR){
    int r = idx >> 7, k = idx & 127;
    ins[r][k] = in[(rb + r) * DIN + k];
  }
  __syncthreads();

  { int r = tid >> 5, j = tid & 31;                    // x = relu(in@W_in + b_in), f32 exact
    for(int cc = 0; cc < 8; ++cc){
      int c = j + 32 * cc;
      float acc = b_in[c];
      for(int k = 0; k < DIN; ++k) acc = fmaf(ins[r][k], W_in[k * H_ + c], acc);
      xs[r][c] = fmaxf(acc, 0.f);
    }
  }
  __syncthreads();

  { int r = tid >> 5, j = tid & 31;                    // zx1 slice (constant over time)
    for(int g = 0; g < 4; ++g){
      int c = g * H_ + jc + j;
      float acc = b1[c];
      for(int k = 0; k < H_; ++k) acc = fmaf(xs[r][k], Wx1[k * ZW + c], acc);
      zx1s[g][r][j] = acc;
    }
  }

  // persistent weight fragments (gate-interleaved cols for recurrent mats)
  const int jbase = jc + (wv << 2);                    // this wave's 4 h-cols
  bf16x8 bw1[8], bx2[8], bh2[8], bwo[8];
#pragma unroll
  for(int k8 = 0; k8 < 8; ++k8){
    bw1[k8] = load_gfrag(Wh1, jbase, 32 * k8, lane);
    bx2[k8] = load_gfrag(Wx2, jbase, 32 * k8, lane);
    bh2[k8] = load_gfrag(Wh2, jbase, 32 * k8, lane);
    bwo[k8] = load_wfrag(W_out, F_, (wv & 3) * 16, 32 * k8, lane);
  }
  const int acol  = lane & 15;
  const int arow  = (lane >> 4) << 2;                  // C/D: row=(lane>>4)*4+reg, col=lane&15 (m89)
  const int gsel  = acol & 3;                          // gate (0=i,1=f,2=g,3=o)
  const bool g2   = (gsel == 2);
  const int jloc  = acol >> 2;                         // h-col within wave's 4
  const float b2r = b2[gsel * H_ + jbase + jloc];
  const float bo  = b_out[(wv & 3) * 16 + acol];
  __syncthreads();

  float zx1r[4];
#pragma unroll
  for(int reg = 0; reg < 4; ++reg) zx1r[reg] = zx1s[gsel][arow + reg][(wv << 2) + jloc];
  float c1r[4] = {0.f,0.f,0.f,0.f}, c2r[4] = {0.f,0.f,0.f,0.f};

  const int uH8   = B_ * H_ / 4;                       // u64 per ping-pong slot
  const int kq    = (lane >> 4) << 3;                  // A-fragment k sub-offset
  const int srow  = tid >> 5;                          // staging row (0..15), 32 thr/row
  const int schk  = tid & 31;                          // staging 16B chunk within row
  const size_t sbase = (size_t)(rb + srow) * 64 + ((size_t)schk << 1);
  uint32_t* const myflag = flags + cid * 128 + (w16 << 4) + wv;     // 8 wg-lines x 8 wave-flags
  const uint32_t* const pollp = flags + cid * 128 + ((lane >> 3) << 4) + (lane & 7);

  // ---------------- 514 phases (R8 protocol, halved sync degree) ----------------
  // phase p: h1(p) [p<T]; h2(p-1) [1<=p<=T]; out(p-2) [p>=2]
  for(int p = 0; p < T_ + 2; ++p){
    // (1) wait for all 64 wave-flags of the cluster >= p
    if(p > 0){
      const uint32_t tgt = (uint32_t)p;
      uint32_t v = __hip_atomic_load(pollp, __ATOMIC_RELAXED, __HIP_MEMORY_SCOPE_AGENT);
      while(!__all((int)(v >= tgt))){
        __builtin_amdgcn_s_sleep(1);
        v = __hip_atomic_load(pollp, __ATOMIC_RELAXED, __HIP_MEMORY_SCOPE_AGENT);
      }
      asm volatile("" ::: "memory");                   // no load hoisting above the poll
    }

    // (2) cooperative stage: h1(p-1), h2(p-2) tiles -> LDS (coalesced rows)
    { const uint64_t* h1rd = h1buf + (size_t)((p - 1) & 1) * uH8;
      const uint64_t* h2rd = h2buf + (size_t)((p - 2) & 1) * uH8;
      uint64_t* d1 = (uint64_t*)&h1s[srow][0];
      uint64_t* d2 = (uint64_t*)&h2s[srow][0];
#pragma unroll
      for(int j = 0; j < 2; ++j)
        d1[(schk << 1) + j] = __hip_atomic_load(h1rd + sbase + j, __ATOMIC_RELAXED, __HIP_MEMORY_SCOPE_AGENT);
#pragma unroll
      for(int j = 0; j < 2; ++j)
        d2[(schk << 1) + j] = __hip_atomic_load(h2rd + sbase + j, __ATOMIC_RELAXED, __HIP_MEMORY_SCOPE_AGENT);
    }
    __syncthreads();

    // A fragments from LDS: row = lane&15, k contiguous
    bf16x8 ah1[8], ah2[8];
#pragma unroll
    for(int k8 = 0; k8 < 8; ++k8){
      int k0 = 32 * k8 + kq;
      ah1[k8] = *(const bf16x8*)&h1s[lane & 15][k0];
      ah2[k8] = *(const bf16x8*)&h2s[lane & 15][k0];
    }

    // (3) layer-1: z1 = h1(p-1)@Wh1 + zx1 -> gates -> publish h1(p)
    if(p < T_){
      f32x4 z1a = {0.f,0.f,0.f,0.f};
#pragma unroll
      for(int k8 = 0; k8 < 8; ++k8) z1a = __builtin_amdgcn_mfma_f32_16x16x32_bf16(ah1[k8], bw1[k8], z1a, 0, 0, 0);
      uint64_t* wr = h1buf + (size_t)(p & 1) * uH8;
#pragma unroll
      for(int reg = 0; reg < 4; ++reg){
        float z  = z1a[reg] + zx1r[reg];
        float a  = gate_act(z, g2);
        float ai = SWZ(a, 0x001C), af = SWZ(a, 0x003C), ag = SWZ(a, 0x005C), ao = SWZ(a, 0x007C);
        float cn = af * c1r[reg] + ai * ag;
        c1r[reg] = cn;
        float hn = ao * tanh_fast(cn);
        float h1v = SWZ(hn, 0x101F);                   // col+1 (lane^4)
        float h2v = SWZ(hn, 0x201F);                   // col+2 (lane^8)
        float h3v = SWZ(hn, 0x301F);                   // col+3 (lane^12)
        if(acol == 0){
          uint64_t pk = (uint64_t)((uint32_t)f2bf(hn) | ((uint32_t)f2bf(h1v) << 16))
                      | ((uint64_t)((uint32_t)f2bf(h2v) | ((uint32_t)f2bf(h3v) << 16)) << 32);
          __hip_atomic_store(wr + (((size_t)(rb + arow + reg) * H_ + jbase) >> 2),
                             pk, __ATOMIC_RELAXED, __HIP_MEMORY_SCOPE_AGENT);
        }
      }
    }

    // (4) layer-2: z2 = h1(p-1)@Wx2 + h2(p-2)@Wh2 + b2 -> publish h2(p-1)
    if(p >= 1 && p <= T_){
      f32x4 zx = {0.f,0.f,0.f,0.f}, zh = {0.f,0.f,0.f,0.f};
#pragma unroll
      for(int k8 = 0; k8 < 8; ++k8){
        zx = __builtin_amdgcn_mfma_f32_16x16x32_bf16(ah1[k8], bx2[k8], zx, 0, 0, 0);
        zh = __builtin_amdgcn_mfma_f32_16x16x32_bf16(ah2[k8], bh2[k8], zh, 0, 0, 0);
      }
      uint64_t* wr = h2buf + (size_t)((p - 1) & 1) * uH8;
#pragma unroll
      for(int reg = 0; reg < 4; ++reg){
        float z  = zx[reg] + zh[reg] + b2r;
        float a  = gate_act(z, g2);
        float ai = SWZ(a, 0x001C), af = SWZ(a, 0x003C), ag = SWZ(a, 0x005C), ao = SWZ(a, 0x007C);
        float cn = af * c2r[reg] + ai * ag;
        c2r[reg] = cn;
        float hn = ao * tanh_fast(cn);
        float h1v = SWZ(hn, 0x101F);
        float h2v = SWZ(hn, 0x201F);
        float h3v = SWZ(hn, 0x301F);
        if(acol == 0){
          uint64_t pk = (uint64_t)((uint32_t)f2bf(hn) | ((uint32_t)f2bf(h1v) << 16))
                      | ((uint64_t)((uint32_t)f2bf(h2v) | ((uint32_t)f2bf(h3v) << 16)) << 32);
          __hip_atomic_store(wr + (((size_t)(rb + arow + reg) * H_ + jbase) >> 2),
                             pk, __ATOMIC_RELAXED, __HIP_MEMORY_SCOPE_AGENT);
        }
      }
    }

    // (5) drain publishes, then per-wave flag (relaxed; ordering via vmcnt drain)
    if(p <= T_){
      asm volatile("s_waitcnt vmcnt(0)" ::: "memory");
      if(lane == 0)
        __hip_atomic_store(myflag, (uint32_t)(p + 1), __ATOMIC_RELAXED, __HIP_MEMORY_SCOPE_AGENT);
    }

    // (6) head (waves 0-3): out(p-2) = h2(p-2)@W_out + b_out
    if(p >= 2 && wv < 4){
      f32x4 oa = {0.f,0.f,0.f,0.f};
#pragma unroll
      for(int k8 = 0; k8 < 8; ++k8) oa = __builtin_amdgcn_mfma_f32_16x16x32_bf16(ah2[k8], bwo[k8], oa, 0, 0, 0);
      const int tout = p - 2;
#pragma unroll
      for(int reg = 0; reg < 4; ++reg)
        out[((size_t)(rb + arow + reg) * T_ + tout) * F_ + (wv & 3) * 16 + acol] = oa[reg] + bo;
    }
  }
}

extern "C" void kernel_launch(void* const* d_in, const int* in_sizes, int n_in,
                              void* d_out, int out_size, void* d_ws, size_t ws_size,
                              hipStream_t stream)
{
  const float* in    = (const float*)d_in[0];
  const float* W_in  = (const float*)d_in[1];
  const float* b_in  = (const float*)d_in[2];
  const float* Wx1   = (const float*)d_in[3];
  const float* Wh1   = (const float*)d_in[4];
  const float* b1    = (const float*)d_in[5];
  const float* Wx2   = (const float*)d_in[6];
  const float* Wh2   = (const float*)d_in[7];
  const float* b2    = (const float*)d_in[8];
  const float* W_out = (const float*)d_in[9];
  const float* b_out = (const float*)d_in[10];
  float* out = (float*)d_out;

  uint8_t* ws = (uint8_t*)d_ws;
  uint32_t* flags = (uint32_t*)ws;                     // 16 clusters x 128 u32 = 8 KB (16K reserved)
  uint64_t* h1buf = (uint64_t*)(ws + 16384);           // [2][256][256] bf16 = 256 KB
  uint64_t* h2buf = (uint64_t*)(ws + 16384 + 2 * B_ * H_ * 2);
  const size_t need = 16384 + 2 * (size_t)(2 * B_ * H_ * 2);
  (void)in_sizes; (void)n_in; (void)out_size; (void)ws_size;

  hipMemsetAsync(d_ws, 0, need, stream);               // zero flags + ping-pong buffers
  hipLaunchKernelGGL(lstm_fused, dim3(NWG), dim3(NTHR), 0, stream,
                     in, W_in, b_in, Wx1, Wh1, b1, Wx2, Wh2, b2, W_out, b_out,
                     out, flags, h1buf, h2buf);
}

// Round 11
// 2135.044 us; speedup vs baseline: 1.5591x; 1.5591x over previous
//
#include <hip/hip_runtime.h>
#include <hip/hip_bf16.h>
#include <stdint.h>

#define B_  256
#define DIN 128
#define H_  256
#define T_  512
#define F_  64
#define ZW  1024   // 4*H

#define WGPC 16    // workgroups per cluster (h-col slices)
#define NWG  256   // 16 clusters x 16 wgs
#define NTHR 256   // 4 waves

#define SLOTU 16384              // u64 per h-slot (256x256 bf16 / 4)
#define POISON64 0x7F7F7F7F7F7F7F7FULL   // bf16 0x7F7F: |x|~1.7e38, unreachable for |h|<=1

typedef __attribute__((ext_vector_type(8))) short bf16x8;
typedef __attribute__((ext_vector_type(4))) float f32x4;

#define SWZ(x,imm) __int_as_float(__builtin_amdgcn_ds_swizzle(__float_as_int(x),(imm)))

__device__ __forceinline__ unsigned short f2bf(float f){
  uint32_t u = __float_as_uint(f);
  uint32_t r = (u + 0x7fffu + ((u >> 16) & 1u)) >> 16;   // RNE
  return (unsigned short)r;
}
__device__ __forceinline__ float gate_act(float z, bool g2){
  float a = g2 ? (-2.f * fabsf(z)) : (-z);
  float t = __expf(a);
  float r = (g2 ? (1.f - t) : 1.f) / (1.f + t);
  return g2 ? copysignf(r, z) : r;
}
__device__ __forceinline__ float tanh_fast(float x){
  float t = __expf(-2.0f * fabsf(x));
  return copysignf((1.0f - t) / (1.0f + t), x);
}

__device__ __forceinline__ bf16x8 load_wfrag(const float* W, int ld, int col, int kbase, int lane){
  int k0 = kbase + ((lane >> 4) << 3);
  int n  = col + (lane & 15);
  bf16x8 r;
#pragma unroll
  for(int j = 0; j < 8; ++j)
    r[j] = (short)f2bf(W[(size_t)(k0 + j) * ld + n]);
  return r;
}
__device__ __forceinline__ bf16x8 load_gfrag(const float* W, int jbase, int kbase, int lane){
  int k0 = kbase + ((lane >> 4) << 3);
  int c  = lane & 15;
  int n  = (c & 3) * H_ + jbase + (c >> 2);
  bf16x8 r;
#pragma unroll
  for(int j = 0; j < 8; ++j)
    r[j] = (short)f2bf(W[(size_t)(k0 + j) * ZW + n]);
  return r;
}
__device__ __forceinline__ uint64_t ld_agent(const uint64_t* a){
  return __hip_atomic_load(a, __ATOMIC_RELAXED, __HIP_MEMORY_SCOPE_AGENT);
}
__device__ __forceinline__ uint64_t ld_retry(const uint64_t* a){
  uint64_t v = ld_agent(a);
  while(v == POISON64){ __builtin_amdgcn_s_sleep(1); v = ld_agent(a); }
  return v;
}

template<bool FULL>
__global__ __launch_bounds__(NTHR, 1)
void lstm_fused(const float* __restrict__ in,  const float* __restrict__ W_in, const float* __restrict__ b_in,
                const float* __restrict__ Wx1, const float* __restrict__ Wh1,  const float* __restrict__ b1,
                const float* __restrict__ Wx2, const float* __restrict__ Wh2,  const float* __restrict__ b2,
                const float* __restrict__ W_out, const float* __restrict__ b_out,
                float* __restrict__ out,
                uint32_t* __restrict__ flags, uint64_t* __restrict__ h1buf, uint64_t* __restrict__ h2buf)
{
  const int tid  = threadIdx.x;
  const int lane = tid & 63;
  const int wv   = tid >> 6;
  const int wg   = blockIdx.x;
  const int cid  = wg >> 4;           // cluster = batch tile of 16 rows
  const int w16  = wg & 15;           // h-col slice within cluster
  const int rb   = cid * 16;
  const int jc   = w16 * 16;

  __shared__ float ins[16][DIN];      // prologue only
  __shared__ float xs[16][H_];        // prologue only
  __shared__ float zx1s[4][16][16];   // prologue only
  __shared__ unsigned short h1s[16][264];
  __shared__ unsigned short h2s[16][264];

  // ---------------- prologue ----------------
  for(int idx = tid; idx < 16 * DIN; idx += NTHR){
    int r = idx >> 7, k = idx & 127;
    ins[r][k] = in[(rb + r) * DIN + k];
  }
  // zero the staging tiles (phases with t<0 read zeros)
  { int r = tid >> 4;
    uint64_t* z1 = (uint64_t*)&h1s[r][0];
    uint64_t* z2 = (uint64_t*)&h2s[r][0];
    for(int j = tid & 15; j < 64; j += 16){ z1[j] = 0; z2[j] = 0; }
  }
  __syncthreads();

  { int r = tid >> 4, j = tid & 15;                    // x = relu(in@W_in + b_in), f32 exact
    for(int cc = 0; cc < 16; ++cc){
      int c = j + 16 * cc;
      float acc = b_in[c];
      for(int k = 0; k < DIN; ++k) acc = fmaf(ins[r][k], W_in[k * H_ + c], acc);
      xs[r][c] = fmaxf(acc, 0.f);
    }
  }
  __syncthreads();

  { int r = tid >> 4, j = tid & 15;                    // zx1 slice (constant over time)
    for(int g = 0; g < 4; ++g){
      int c = g * H_ + jc + j;
      float acc = b1[c];
      for(int k = 0; k < H_; ++k) acc = fmaf(xs[r][k], Wx1[k * ZW + c], acc);
      zx1s[g][r][j] = acc;
    }
  }

  const int jbase = jc + (wv << 2);                    // this wave's 4 h-cols
  bf16x8 bw1[8], bx2[8], bh2[8], bwo[8];
#pragma unroll
  for(int k8 = 0; k8 < 8; ++k8){
    bw1[k8] = load_gfrag(Wh1, jbase, 32 * k8, lane);
    bx2[k8] = load_gfrag(Wx2, jbase, 32 * k8, lane);
    bh2[k8] = load_gfrag(Wh2, jbase, 32 * k8, lane);
    bwo[k8] = load_wfrag(W_out, F_, wv * 16, 32 * k8, lane);
  }
  const int acol  = lane & 15;
  const int arow  = (lane >> 4) << 2;                  // C/D: row=(lane>>4)*4+reg, col=lane&15 (m89)
  const int gsel  = acol & 3;                          // gate (0=i,1=f,2=g,3=o)
  const bool g2   = (gsel == 2);
  const int jloc  = acol >> 2;
  const float b2r = b2[gsel * H_ + jbase + jloc];
  const float bo  = b_out[wv * 16 + acol];
  __syncthreads();

  float zx1r[4];
#pragma unroll
  for(int reg = 0; reg < 4; ++reg) zx1r[reg] = zx1s[gsel][arow + reg][(wv << 2) + jloc];
  float c1r[4] = {0.f,0.f,0.f,0.f}, c2r[4] = {0.f,0.f,0.f,0.f};

  const int kq    = (lane >> 4) << 3;
  const int srow  = tid >> 4;                          // staging row (0..15)
  const int schk  = tid & 15;                          // staging 32B chunk
  const size_t sbase = (size_t)(rb + srow) * 64 + ((size_t)schk << 2);
  uint32_t* const myflag = flags + (cid << 8) + (w16 << 4) + wv;
  const uint32_t* const pollp = flags + (cid << 8) + ((lane >> 2) << 4) + (lane & 3);

  // ---------------- 514 phases ----------------
  // phase p: h1(p) [p<T]; h2(p-1) [1<=p<=T]; out(p-2) [p>=2]
  for(int p = 0; p < T_ + 2; ++p){
    if(!FULL && p > 0){                                // flag handshake (fallback mode only)
      const uint32_t tgt = (uint32_t)p;
      uint32_t v = __hip_atomic_load(pollp, __ATOMIC_RELAXED, __HIP_MEMORY_SCOPE_AGENT);
      while(!__all((int)(v >= tgt))){
        __builtin_amdgcn_s_sleep(1);
        v = __hip_atomic_load(pollp, __ATOMIC_RELAXED, __HIP_MEMORY_SCOPE_AGENT);
      }
      asm volatile("" ::: "memory");
    }

    // stage h1(p-1), h2(p-2) -> LDS. FULL: poison-retry on write-once history.
    if(FULL){
      if(p >= 1 && p <= T_){
        const uint64_t* s1 = h1buf + (size_t)(p - 1) * SLOTU + sbase;
        uint64_t* d1 = (uint64_t*)&h1s[srow][0];
#pragma unroll
        for(int j = 0; j < 4; ++j) d1[(schk << 2) + j] = ld_retry(s1 + j);
      }
      if(p >= 2){
        const uint64_t* s2 = h2buf + (size_t)(p - 2) * SLOTU + sbase;
        uint64_t* d2 = (uint64_t*)&h2s[srow][0];
#pragma unroll
        for(int j = 0; j < 4; ++j) d2[(schk << 2) + j] = ld_retry(s2 + j);
      }
    } else {
      const uint64_t* s1 = h1buf + (size_t)((p - 1) & 1) * SLOTU + sbase;
      const uint64_t* s2 = h2buf + (size_t)((p - 2) & 1) * SLOTU + sbase;
      uint64_t* d1 = (uint64_t*)&h1s[srow][0];
      uint64_t* d2 = (uint64_t*)&h2s[srow][0];
#pragma unroll
      for(int j = 0; j < 4; ++j) d1[(schk << 2) + j] = ld_agent(s1 + j);
#pragma unroll
      for(int j = 0; j < 4; ++j) d2[(schk << 2) + j] = ld_agent(s2 + j);
    }
    __syncthreads();

    bf16x8 ah1[8], ah2[8];
#pragma unroll
    for(int k8 = 0; k8 < 8; ++k8){
      int k0 = 32 * k8 + kq;
      ah1[k8] = *(const bf16x8*)&h1s[lane & 15][k0];
      ah2[k8] = *(const bf16x8*)&h2s[lane & 15][k0];
    }

    // layer-1: z1 = h1(p-1)@Wh1 + zx1 -> gates -> publish h1(p)
    if(p < T_){
      f32x4 z1a = {0.f,0.f,0.f,0.f};
#pragma unroll
      for(int k8 = 0; k8 < 8; ++k8) z1a = __builtin_amdgcn_mfma_f32_16x16x32_bf16(ah1[k8], bw1[k8], z1a, 0, 0, 0);
      uint64_t* wr = h1buf + (FULL ? (size_t)p : (size_t)(p & 1)) * SLOTU;
#pragma unroll
      for(int reg = 0; reg < 4; ++reg){
        float z  = z1a[reg] + zx1r[reg];
        float a  = gate_act(z, g2);
        float ai = SWZ(a, 0x001C), af = SWZ(a, 0x003C), ag = SWZ(a, 0x005C), ao = SWZ(a, 0x007C);
        float cn = af * c1r[reg] + ai * ag;
        c1r[reg] = cn;
        float hn = ao * tanh_fast(cn);
        float h1v = SWZ(hn, 0x101F);
        float h2v = SWZ(hn, 0x201F);
        float h3v = SWZ(hn, 0x301F);
        if(acol == 0){
          uint64_t pk = (uint64_t)((uint32_t)f2bf(hn) | ((uint32_t)f2bf(h1v) << 16))
                      | ((uint64_t)((uint32_t)f2bf(h2v) | ((uint32_t)f2bf(h3v) << 16)) << 32);
          __hip_atomic_store(wr + (((size_t)(rb + arow + reg) * H_ + jbase) >> 2),
                             pk, __ATOMIC_RELAXED, __HIP_MEMORY_SCOPE_AGENT);
        }
      }
    }

    // layer-2: z2 = h1(p-1)@Wx2 + h2(p-2)@Wh2 + b2 -> publish h2(p-1)
    if(p >= 1 && p <= T_){
      f32x4 zx = {0.f,0.f,0.f,0.f}, zh = {0.f,0.f,0.f,0.f};
#pragma unroll
      for(int k8 = 0; k8 < 8; ++k8){
        zx = __builtin_amdgcn_mfma_f32_16x16x32_bf16(ah1[k8], bx2[k8], zx, 0, 0, 0);
        zh = __builtin_amdgcn_mfma_f32_16x16x32_bf16(ah2[k8], bh2[k8], zh, 0, 0, 0);
      }
      uint64_t* wr = h2buf + (FULL ? (size_t)(p - 1) : (size_t)((p - 1) & 1)) * SLOTU;
#pragma unroll
      for(int reg = 0; reg < 4; ++reg){
        float z  = zx[reg] + zh[reg] + b2r;
        float a  = gate_act(z, g2);
        float ai = SWZ(a, 0x001C), af = SWZ(a, 0x003C), ag = SWZ(a, 0x005C), ao = SWZ(a, 0x007C);
        float cn = af * c2r[reg] + ai * ag;
        c2r[reg] = cn;
        float hn = ao * tanh_fast(cn);
        float h1v = SWZ(hn, 0x101F);
        float h2v = SWZ(hn, 0x201F);
        float h3v = SWZ(hn, 0x301F);
        if(acol == 0){
          uint64_t pk = (uint64_t)((uint32_t)f2bf(hn) | ((uint32_t)f2bf(h1v) << 16))
                      | ((uint64_t)((uint32_t)f2bf(h2v) | ((uint32_t)f2bf(h3v) << 16)) << 32);
          __hip_atomic_store(wr + (((size_t)(rb + arow + reg) * H_ + jbase) >> 2),
                             pk, __ATOMIC_RELAXED, __HIP_MEMORY_SCOPE_AGENT);
        }
      }
    }

    if(!FULL && p <= T_){                              // drain + flag (fallback only)
      asm volatile("s_waitcnt vmcnt(0)" ::: "memory");
      if(lane == 0)
        __hip_atomic_store(myflag, (uint32_t)(p + 1), __ATOMIC_RELAXED, __HIP_MEMORY_SCOPE_AGENT);
    }

    // head: out(p-2) = h2(p-2)@W_out + b_out
    if(p >= 2){
      f32x4 oa = {0.f,0.f,0.f,0.f};
#pragma unroll
      for(int k8 = 0; k8 < 8; ++k8) oa = __builtin_amdgcn_mfma_f32_16x16x32_bf16(ah2[k8], bwo[k8], oa, 0, 0, 0);
      const int tout = p - 2;
#pragma unroll
      for(int reg = 0; reg < 4; ++reg)
        out[((size_t)(rb + arow + reg) * T_ + tout) * F_ + wv * 16 + acol] = oa[reg] + bo;
    }

    __syncthreads();   // intra-wg: nobody re-stages LDS while others still read fragments
  }
}

extern "C" void kernel_launch(void* const* d_in, const int* in_sizes, int n_in,
                              void* d_out, int out_size, void* d_ws, size_t ws_size,
                              hipStream_t stream)
{
  const float* in    = (const float*)d_in[0];
  const float* W_in  = (const float*)d_in[1];
  const float* b_in  = (const float*)d_in[2];
  const float* Wx1   = (const float*)d_in[3];
  const float* Wh1   = (const float*)d_in[4];
  const float* b1    = (const float*)d_in[5];
  const float* Wx2   = (const float*)d_in[6];
  const float* Wh2   = (const float*)d_in[7];
  const float* b2    = (const float*)d_in[8];
  const float* W_out = (const float*)d_in[9];
  const float* b_out = (const float*)d_in[10];
  float* out = (float*)d_out;
  (void)in_sizes; (void)n_in; (void)out_size;

  uint8_t* ws = (uint8_t*)d_ws;
  const size_t slotB  = (size_t)B_ * H_ * 2;           // 128 KB per h-slot
  const size_t histB  = (size_t)T_ * slotB;            // 64 MB per layer history
  const size_t needF  = 16384 + 2 * histB;             // full-history mode
  const size_t needR  = 16384 + 2 * (2 * slotB);       // ping-pong fallback (R8)

  uint32_t* flags = (uint32_t*)ws;
  uint64_t* h1b   = (uint64_t*)(ws + 16384);

  if(ws_size >= needF){
    uint64_t* h2b = (uint64_t*)(ws + 16384 + histB);
    hipMemsetAsync(ws, 0, 16384, stream);              // flags (unused in FULL)
    hipMemsetAsync(ws + 16384, 0x7F, 2 * histB, stream); // poison histories
    hipLaunchKernelGGL(lstm_fused<true>, dim3(NWG), dim3(NTHR), 0, stream,
                       in, W_in, b_in, Wx1, Wh1, b1, Wx2, Wh2, b2, W_out, b_out,
                       out, flags, h1b, h2b);
  } else {
    uint64_t* h2b = (uint64_t*)(ws + 16384 + 2 * slotB);
    hipMemsetAsync(ws, 0, needR, stream);              // flags + ping-pong zeros
    hipLaunchKernelGGL(lstm_fused<false>, dim3(NWG), dim3(NTHR), 0, stream,
                       in, W_in, b_in, Wx1, Wh1, b1, Wx2, Wh2, b2, W_out, b_out,
                       out, flags, h1b, h2b);
  }
}